// Round 3
// baseline (2525.127 us; speedup 1.0000x reference)
//
#include <hip/hip_runtime.h>
#include <hip/hip_fp16.h>

#define N 512
#define WAVES 16
#define BLOCK (WAVES * 64)          // 1024 threads, 16 waves
#define RPW   (N / WAVES)           // 32 rows per wave (k = 0..31)
#define REG_K 12                    // k-slices held in VGPRs   (48 VGPRs, fp16)
#define LDS_K 7                     // k-slices held in LDS     (112 KiB)
#define GLB_K (RPW - REG_K - LDS_K) // 13 k-slices in global    (208 KB/matrix)

// Sinkhorn, materialized-exp form. E = exp(a) fp16, partitioned by OWNERSHIP:
// thread (wave,lane) owns rows k*16+wave (k=0..31), cols 8*lane..8*lane+7.
// E is only ever re-read by its owning thread => it can live in registers
// (k<REG_K), LDS (k<REG_K+LDS_K), and a small global remainder. Sweep global
// traffic drops 71% vs full-global E; reg/LDS rows have ~zero load latency.
//   row pass:  S_i = sum_j E_ij * wv_j    (wv_j = 1/t_j)
//   col pass:  t_j = sum_i E_ij / S_i
//   output:    out = exp(a) * (1/S_i) * (1/t_j)  -- re-reads fp32 A, so
//              numerics are identical to the previous (passing) version.
// Eg occupies the first GLB_K*16KB of Ob; it is dead before the output pass
// overwrites it (all sweep reads complete at the final barrier).

#define PASS0_ROW(k, U0, U1, U2, U3) {                                        \
    const int row = (k) * WAVES + wave;                                       \
    const float4* R = (const float4*)(Ab + (size_t)row * N);                  \
    const float4 x0 = R[2 * lane];                                            \
    const float4 x1 = R[2 * lane + 1];                                        \
    const float e0 = __expf(x0.x), e1 = __expf(x0.y),                         \
                e2 = __expf(x0.z), e3 = __expf(x0.w);                         \
    const float e4 = __expf(x1.x), e5 = __expf(x1.y),                         \
                e6 = __expf(x1.z), e7 = __expf(x1.w);                         \
    __half2 h01 = __floats2half2_rn(e0, e1), h23 = __floats2half2_rn(e2, e3); \
    __half2 h45 = __floats2half2_rn(e4, e5), h67 = __floats2half2_rn(e6, e7); \
    U0 = *(const unsigned*)&h01; U1 = *(const unsigned*)&h23;                 \
    U2 = *(const unsigned*)&h45; U3 = *(const unsigned*)&h67;                 \
    float S = ((e0 + e1) + (e2 + e3)) + ((e4 + e5) + (e6 + e7));              \
    _Pragma("unroll") for (int m = 1; m < 64; m <<= 1)                        \
        S += __shfl_xor(S, m, 64);                                            \
    const float inv = 1.0f / S;                                               \
    if (lane == 0) sinvS[row] = inv;                                          \
    t0 += e0 * inv; t1 += e1 * inv; t2 += e2 * inv; t3 += e3 * inv;           \
    t4 += e4 * inv; t5 += e5 * inv; t6 += e6 * inv; t7 += e7 * inv; }

#define SWEEP_ROW(k, U0, U1, U2, U3) {                                        \
    const int row = (k) * WAVES + wave;                                       \
    const float2 f01 = __half22float2(*(const __half2*)&(U0));                \
    const float2 f23 = __half22float2(*(const __half2*)&(U1));                \
    const float2 f45 = __half22float2(*(const __half2*)&(U2));                \
    const float2 f67 = __half22float2(*(const __half2*)&(U3));                \
    const float s01 = f01.x * wa.x + f01.y * wa.y;                            \
    const float s23 = f23.x * wa.z + f23.y * wa.w;                            \
    const float s45 = f45.x * wb.x + f45.y * wb.y;                            \
    const float s67 = f67.x * wb.z + f67.y * wb.w;                            \
    float S = (s01 + s23) + (s45 + s67);                                      \
    _Pragma("unroll") for (int m = 1; m < 64; m <<= 1)                        \
        S += __shfl_xor(S, m, 64);                                            \
    const float inv = 1.0f / S;                                               \
    if (lane == 0) sinvS[row] = inv;                                          \
    t0 += f01.x * inv; t1 += f01.y * inv;                                     \
    t2 += f23.x * inv; t3 += f23.y * inv;                                     \
    t4 += f45.x * inv; t5 += f45.y * inv;                                     \
    t6 += f67.x * inv; t7 += f67.y * inv; }

__global__ __launch_bounds__(BLOCK, 4)
void sinkhorn_kernel(const float* __restrict__ A, float* __restrict__ Out) {
    __shared__ float swv[N];              // 1/t_j               (2 KiB)
    __shared__ float sinvS[N];            // 1/S_i               (2 KiB)
    __shared__ float spart[WAVES][N];     // col-sum partials   (32 KiB)
    __shared__ uint4 Esh[LDS_K * BLOCK];  // E k-slices 12..18 (112 KiB)

    const float* __restrict__ Ab = A   + (size_t)blockIdx.x * (N * N);
    float* __restrict__ Ob       = Out + (size_t)blockIdx.x * (N * N);
    uint4* __restrict__ Eg       = (uint4*)Ob;   // first GLB_K*16KB of Ob

    const int tid  = threadIdx.x;
    const int lane = tid & 63;
    const int wave = tid >> 6;

    unsigned eR[REG_K][4];   // fp16-packed E, rows k*16+wave, cols 8L..8L+7

    // ---------------- pass 0: E = exp(a); S_i; col partials ----------------
    {
        float t0=0.f,t1=0.f,t2=0.f,t3=0.f,t4=0.f,t5=0.f,t6=0.f,t7=0.f;
        #pragma unroll
        for (int k = 0; k < REG_K; ++k)
            PASS0_ROW(k, eR[k][0], eR[k][1], eR[k][2], eR[k][3]);
        #pragma unroll
        for (int k = REG_K; k < REG_K + LDS_K; ++k) {
            unsigned u0,u1,u2,u3; PASS0_ROW(k, u0,u1,u2,u3);
            Esh[(k - REG_K) * BLOCK + tid] = make_uint4(u0,u1,u2,u3);
        }
        #pragma unroll 2
        for (int k = REG_K + LDS_K; k < RPW; ++k) {
            unsigned u0,u1,u2,u3; PASS0_ROW(k, u0,u1,u2,u3);
            Eg[(size_t)(k - REG_K - LDS_K) * BLOCK + tid] = make_uint4(u0,u1,u2,u3);
        }
        ((float4*)spart[wave])[2 * lane]     = make_float4(t0, t1, t2, t3);
        ((float4*)spart[wave])[2 * lane + 1] = make_float4(t4, t5, t6, t7);
        __syncthreads();
        if (tid < N) {
            float s = 0.f;
            #pragma unroll
            for (int w = 0; w < WAVES; ++w) s += spart[w][tid];
            swv[tid] = 1.0f / s;            // 1/t_j = exp(-v_j)
        }
        __syncthreads();
    }

    // ---------------- passes 1..9: reg/LDS/global fused sweeps -------------
    for (int pass = 1; pass < 10; ++pass) {
        const float4 wa = ((const float4*)swv)[2 * lane];      // cols 8L..8L+3
        const float4 wb = ((const float4*)swv)[2 * lane + 1];  // cols 8L+4..+7
        float t0=0.f,t1=0.f,t2=0.f,t3=0.f,t4=0.f,t5=0.f,t6=0.f,t7=0.f;

        // global rows first (loads pipeline while reg/LDS rows compute)
        #pragma unroll 2
        for (int k = REG_K + LDS_K; k < RPW; ++k) {
            const uint4 g = Eg[(size_t)(k - REG_K - LDS_K) * BLOCK + tid];
            SWEEP_ROW(k, g.x, g.y, g.z, g.w);
        }
        // register-resident rows (zero memory traffic)
        #pragma unroll
        for (int k = 0; k < REG_K; ++k)
            SWEEP_ROW(k, eR[k][0], eR[k][1], eR[k][2], eR[k][3]);
        // LDS-resident rows (conflict-free b128 at tid*16B)
        #pragma unroll
        for (int k = REG_K; k < REG_K + LDS_K; ++k) {
            const uint4 g = Esh[(k - REG_K) * BLOCK + tid];
            SWEEP_ROW(k, g.x, g.y, g.z, g.w);
        }

        ((float4*)spart[wave])[2 * lane]     = make_float4(t0, t1, t2, t3);
        ((float4*)spart[wave])[2 * lane + 1] = make_float4(t4, t5, t6, t7);
        __syncthreads();
        if (tid < N) {
            float s = 0.f;
            #pragma unroll
            for (int w = 0; w < WAVES; ++w) s += spart[w][tid];
            swv[tid] = 1.0f / s;
        }
        __syncthreads();
    }

    // ------- output: out = exp(a) * (1/S_i) * (1/t_j), from fp32 A ---------
    // Eg region (first GLB_K*16KB of Ob) is dead now; overwriting is safe.
    {
        const float4 w0 = ((const float4*)swv)[lane];
        const float4 w1 = ((const float4*)swv)[lane + 64];
        #pragma unroll 4
        for (int k = 0; k < RPW; ++k) {
            const int row = k * WAVES + wave;
            const float4* R = (const float4*)(Ab + (size_t)row * N);
            float4*       W = (float4*)(Ob + (size_t)row * N);
            const float4 x0 = R[lane];
            const float4 x1 = R[lane + 64];
            const float c = sinvS[row];

            float4 o0, o1;
            o0.x = __expf(x0.x) * (c * w0.x);
            o0.y = __expf(x0.y) * (c * w0.y);
            o0.z = __expf(x0.z) * (c * w0.z);
            o0.w = __expf(x0.w) * (c * w0.w);
            o1.x = __expf(x1.x) * (c * w1.x);
            o1.y = __expf(x1.y) * (c * w1.y);
            o1.z = __expf(x1.z) * (c * w1.z);
            o1.w = __expf(x1.w) * (c * w1.w);

            W[lane]      = o0;
            W[lane + 64] = o1;
        }
    }
}

extern "C" void kernel_launch(void* const* d_in, const int* in_sizes, int n_in,
                              void* d_out, int out_size, void* d_ws, size_t ws_size,
                              hipStream_t stream) {
    const float* s = (const float*)d_in[0];
    float* out = (float*)d_out;
    const int nmat = in_sizes[0] / (N * N);   // 256
    sinkhorn_kernel<<<nmat, BLOCK, 0, stream>>>(s, out);
}